// Round 6
// baseline (167.598 us; speedup 1.0000x reference)
//
#include <hip/hip_runtime.h>
#include <math.h>

// Problem constants
#define NBINS 2049       // F
#define NXC   599        // 2*NLAG-1
#define LST   640        // ws row stride (floats)
#define TWO_PI 6.283185307179586f

// complex LDS padding: +2 complex per 64 → 16B alignment kept, banks spread
#define CPAD(c) ((c) + 2 * ((c) >> 6))

struct cpx { float r, i; };
__device__ inline cpx cmul(cpx a, cpx b) { return cpx{a.r * b.r - a.i * b.i, a.r * b.i + a.i * b.r}; }

__device__ inline void dft4i(float& r0, float& i0, float& r1, float& i1,
                             float& r2, float& i2, float& r3, float& i3) {
    // inverse (e^{+i}) 4-point DFT in place, natural order
    float t0r = r0 + r2, t0i = i0 + i2;
    float t1r = r0 - r2, t1i = i0 - i2;
    float t2r = r1 + r3, t2i = i1 + i3;
    float t3r = r1 - r3, t3i = i1 - i3;
    r0 = t0r + t2r; i0 = t0i + t2i;
    r2 = t0r - t2r; i2 = t0i - t2i;
    r1 = t1r - t3i; i1 = t1i + t3r;   // t1 + i*t3
    r3 = t1r + t3i; i3 = t1i - t3r;   // t1 - i*t3
}

__device__ inline void radix8_bfly(float r[8], float im[8]) {
    // inverse 8-point DFT, natural order in/out
    float er0 = r[0], ei0 = im[0], er1 = r[2], ei1 = im[2];
    float er2 = r[4], ei2 = im[4], er3 = r[6], ei3 = im[6];
    float or0 = r[1], oi0 = im[1], or1 = r[3], oi1 = im[3];
    float or2 = r[5], oi2 = im[5], or3 = r[7], oi3 = im[7];
    dft4i(er0, ei0, er1, ei1, er2, ei2, er3, ei3);
    dft4i(or0, oi0, or1, oi1, or2, oi2, or3, oi3);
    const float C = 0.70710678118654752f;
    float w1r = C * (or1 - oi1), w1i = C * (or1 + oi1);   // e^{i pi/4} * o1
    float w2r = -oi2,            w2i = or2;               // i * o2
    float w3r = -C * (or3 + oi3), w3i = C * (or3 - oi3);  // e^{3i pi/4} * o3
    r[0] = er0 + or0; im[0] = ei0 + oi0;
    r[4] = er0 - or0; im[4] = ei0 - oi0;
    r[1] = er1 + w1r; im[1] = ei1 + w1i;
    r[5] = er1 - w1r; im[5] = ei1 - w1i;
    r[2] = er2 + w2r; im[2] = ei2 + w2i;
    r[6] = er2 - w2r; im[6] = ei2 - w2i;
    r[3] = er3 + w3r; im[3] = ei3 + w3i;
    r[7] = er3 - w3r; im[7] = ei3 - w3i;
}

// inverse 16-point DFT, natural order in/out (DIT: evens/odds radix-8 + w16 twiddles)
__device__ inline void dft16i(float xr[16], float xi[16]) {
    float er[8], ei[8], odr[8], odi[8];
#pragma unroll
    for (int k = 0; k < 8; ++k) {
        er[k] = xr[2 * k];      ei[k] = xi[2 * k];
        odr[k] = xr[2 * k + 1]; odi[k] = xi[2 * k + 1];
    }
    radix8_bfly(er, ei);
    radix8_bfly(odr, odi);
    const float c1 = 0.92387953251128675613f;   // cos(pi/8)
    const float s1 = 0.38268343236508977173f;   // sin(pi/8)
    const float C  = 0.70710678118654752440f;
    float tr[8], td[8];
    tr[0] = odr[0];                      td[0] = odi[0];
    tr[1] = c1 * odr[1] - s1 * odi[1];   td[1] = c1 * odi[1] + s1 * odr[1];
    tr[2] = C * (odr[2] - odi[2]);       td[2] = C * (odr[2] + odi[2]);
    tr[3] = s1 * odr[3] - c1 * odi[3];   td[3] = s1 * odi[3] + c1 * odr[3];
    tr[4] = -odi[4];                     td[4] = odr[4];
    tr[5] = -s1 * odr[5] - c1 * odi[5];  td[5] = -s1 * odi[5] + c1 * odr[5];
    tr[6] = -C * (odr[6] + odi[6]);      td[6] = C * (odr[6] - odi[6]);
    tr[7] = -c1 * odr[7] - s1 * odi[7];  td[7] = -c1 * odi[7] + s1 * odr[7];
#pragma unroll
    for (int k = 0; k < 8; ++k) {
        xr[k]     = er[k] + tr[k];  xi[k]     = ei[k] + td[k];
        xr[k + 8] = er[k] - tr[k];  xi[k + 8] = ei[k] - td[k];
    }
}

// Apply w^k (k=1..15), w = (cs, sn). Log-depth product tree; 15 independent multiplies.
__device__ inline void apply_tw15(float zr[16], float zi[16], float cs, float sn) {
    cpx w[16];
    w[1]  = cpx{cs, sn};
    w[2]  = cmul(w[1], w[1]);
    w[3]  = cmul(w[1], w[2]);
    w[4]  = cmul(w[2], w[2]);
    w[5]  = cmul(w[2], w[3]);
    w[6]  = cmul(w[3], w[3]);
    w[7]  = cmul(w[3], w[4]);
    w[8]  = cmul(w[4], w[4]);
    w[9]  = cmul(w[4], w[5]);
    w[10] = cmul(w[5], w[5]);
    w[11] = cmul(w[5], w[6]);
    w[12] = cmul(w[6], w[6]);
    w[13] = cmul(w[6], w[7]);
    w[14] = cmul(w[7], w[7]);
    w[15] = cmul(w[7], w[8]);
#pragma unroll
    for (int k = 1; k < 16; ++k) {
        float a = zr[k] * w[k].r - zi[k] * w[k].i;
        float b = zr[k] * w[k].i + zi[k] * w[k].r;
        zr[k] = a; zi[k] = b;
    }
}

// One row's pack + 2048-pt inverse FFT (radix 16/16/8, 2 LDS exchanges) + lag store.
// xr_/xi_ hold this row's X values pre-scaled by h = 0.5/2048; S holds the same
// (mirror source). Leaves stage-3 LDS reads complete; caller barriers before reuse.
__device__ inline void fft_row(const float xr_[16], const float xi_[16],
                               float2* __restrict__ S, int tt,
                               float* __restrict__ wrow) {
    const float WC[16] = { 1.0f, 0.98078528040323044913f, 0.92387953251128675613f,
        0.83146961230254523708f, 0.70710678118654752440f, 0.55557023301960222474f,
        0.38268343236508977173f, 0.19509032201612826785f, 0.0f,
        -0.19509032201612826785f, -0.38268343236508977173f, -0.55557023301960222474f,
        -0.70710678118654752440f, -0.83146961230254523708f, -0.92387953251128675613f,
        -0.98078528040323044913f };
    const float WS[16] = { 0.0f, 0.19509032201612826785f, 0.38268343236508977173f,
        0.55557023301960222474f, 0.70710678118654752440f, 0.83146961230254523708f,
        0.92387953251128675613f, 0.98078528040323044913f, 1.0f,
        0.98078528040323044913f, 0.92387953251128675613f, 0.83146961230254523708f,
        0.70710678118654752440f, 0.55557023301960222474f, 0.38268343236508977173f,
        0.19509032201612826785f };
    float zr[16], zi[16];
    float sn, cs;

    // ---- pack: Z[c] = E + i*t_c*D, mirror X[2048-c] from LDS (all pre-scaled) ----
    __sincosf((float)tt * (TWO_PI / 4096.0f), &sn, &cs);
#pragma unroll
    for (int j = 0; j < 16; ++j) {
        float2 m = S[CPAD(2048 - tt - 128 * j)];   // tt=0,j=0 → slot 2112 (bin 2048)
        float er = xr_[j] + m.x, ei = xi_[j] - m.y;
        float dr = xr_[j] - m.x, di = xi_[j] + m.y;
        float twr = cs * WC[j] - sn * WS[j];
        float twi = cs * WS[j] + sn * WC[j];
        zr[j] = er - twi * dr - twr * di;
        zi[j] = ei + twr * dr - twi * di;
    }

    // ---- stage 1: L=2048, radix-16, span=128, i = tt ----
    dft16i(zr, zi);
    __sincosf((float)tt * (TWO_PI / 2048.0f), &sn, &cs);
    apply_tw15(zr, zi, cs, sn);
    __syncthreads();   // all mirror reads complete before X is overwritten
#pragma unroll
    for (int k = 0; k < 16; ++k)
        S[CPAD(tt + 128 * k)] = make_float2(zr[k], zi[k]);
    __syncthreads();

    // ---- stage 2: L=128, radix-16, span=8; in-place (read set == write set) ----
    const int s2 = tt >> 3, i2 = tt & 7;
    const int base2 = 128 * s2 + i2;
#pragma unroll
    for (int j = 0; j < 16; ++j) {
        float2 v = S[CPAD(base2 + 8 * j)];
        zr[j] = v.x; zi[j] = v.y;
    }
    dft16i(zr, zi);
    __sincosf((float)i2 * (TWO_PI / 128.0f), &sn, &cs);
    apply_tw15(zr, zi, cs, sn);
#pragma unroll
    for (int k = 0; k < 16; ++k)
        S[CPAD(base2 + 8 * k)] = make_float2(zr[k], zi[k]);
    __syncthreads();

    // ---- stage 3: L=8, radix-8 on sub-blocks sb = 2tt, 2tt+1 (slots 16tt..16tt+15) ----
    float ar[8], ai[8], br[8], bi[8];
#pragma unroll
    for (int r = 0; r < 4; ++r) {
        float4 v = *(const float4*)&S[CPAD(16 * tt + 2 * r)];
        ar[2 * r] = v.x; ai[2 * r] = v.y; ar[2 * r + 1] = v.z; ai[2 * r + 1] = v.w;
    }
#pragma unroll
    for (int r = 0; r < 4; ++r) {
        float4 v = *(const float4*)&S[CPAD(16 * tt + 8 + 2 * r)];
        br[2 * r] = v.x; bi[2 * r] = v.y; br[2 * r + 1] = v.z; bi[2 * r + 1] = v.w;
    }
    radix8_bfly(ar, ai);   // only y[0], y[7] consumed; DCE trims the rest
    radix8_bfly(br, bi);

    // sub-block sb = 16*k1 + k2 holds spectral m = m0 + 256*k3, m0 = k1 + 16*k2.
    // lag map: m0<=149: Re->l=2m0+299, Im->l=2m0+300 (from y[0]);
    //          m0>=107: Re->l=2m0-213, Im->l=2m0-212 (from y[7]); m0==106: Im->l=0.
    {
        int sb = 2 * tt;
        int m0 = (sb >> 4) + 16 * (sb & 15);
        if (m0 <= 149) { wrow[2 * m0 + 299] = ar[0]; wrow[2 * m0 + 300] = ai[0]; }
        if (m0 >= 107)      { wrow[2 * m0 - 213] = ar[7]; wrow[2 * m0 - 212] = ai[7]; }
        else if (m0 == 106) { wrow[0] = ai[7]; }
    }
    {
        int sb = 2 * tt + 1;
        int m0 = (sb >> 4) + 16 * (sb & 15);
        if (m0 <= 149) { wrow[2 * m0 + 299] = br[0]; wrow[2 * m0 + 300] = bi[0]; }
        if (m0 >= 107)      { wrow[2 * m0 - 213] = br[7]; wrow[2 * m0 - 212] = bi[7]; }
        else if (m0 == 106) { wrow[0] = bi[7]; }
    }
}

// Kernel 1: TWO (b,c) rows per 128-thread block, processed sequentially with
// cross-row prefetch: row1's global loads are issued right after row0's phase-0
// LDS writes (row0 load regs freed) and land under row0's entire FFT (~2000 cyc).
__global__ __launch_bounds__(128, 4) void k1_fft(const float2* __restrict__ d1,
                                                 const float2* __restrict__ d2,
                                                 float* __restrict__ ws) {
    __shared__ float2 S[2113];   // CPAD(0..2047) + slot CPAD(2048)=2112; 16.9 KB
    const int tt = threadIdx.x;  // 0..127
    const int row0 = blockIdx.x << 1;
    const float h = 2.44140625e-4f;   // 0.5 / 2048 (irfft scale folded into X)

    const float2* p1 = d1 + (long)row0 * NBINS;
    const float2* p2 = d2 + (long)row0 * NBINS;
    const float2* q1 = p1 + NBINS;
    const float2* q2 = p2 + NBINS;

    // ---- row0 phase 0: load own bins, X = h*conj(c1)*c2 → regs + LDS ----
    float x0r[16], x0i[16];
#pragma unroll
    for (int j = 0; j < 16; ++j) {
        int c = tt + 128 * j;
        float2 a = p1[c], bb = p2[c];
        x0r[j] = h * (a.x * bb.x + a.y * bb.y);
        x0i[j] = h * (a.x * bb.y - a.y * bb.x);
        if (c == 0) x0i[j] = 0.0f;            // bin 0 imag zeroed
        S[CPAD(c)] = make_float2(x0r[j], x0i[j]);
    }
    if (tt == 127) {   // bin 2048 (Nyquist), imag zeroed (pocketfft c2r semantics)
        float2 a = p1[2048], bb = p2[2048];
        S[2112] = make_float2(h * (a.x * bb.x + a.y * bb.y), 0.0f);
    }

    // ---- prefetch row1 raw data (issues now; consumed after row0's FFT) ----
    float2 a1[16], b1[16], ny1, ny2;
#pragma unroll
    for (int j = 0; j < 16; ++j) {
        int c = tt + 128 * j;
        a1[j] = q1[c];
        b1[j] = q2[c];
    }
    if (tt == 127) { ny1 = q1[2048]; ny2 = q2[2048]; }

    __syncthreads();
    fft_row(x0r, x0i, S, tt, ws + (long)row0 * LST);
    __syncthreads();   // stage-3 reads done before phase-0 overwrite

    // ---- row1 phase 0 from prefetched regs ----
    float x1r[16], x1i[16];
#pragma unroll
    for (int j = 0; j < 16; ++j) {
        int c = tt + 128 * j;
        x1r[j] = h * (a1[j].x * b1[j].x + a1[j].y * b1[j].y);
        x1i[j] = h * (a1[j].x * b1[j].y - a1[j].y * b1[j].x);
        if (c == 0) x1i[j] = 0.0f;
        S[CPAD(c)] = make_float2(x1r[j], x1i[j]);
    }
    if (tt == 127) {
        S[2112] = make_float2(h * (ny1.x * ny2.x + ny1.y * ny2.y), 0.0f);
    }
    __syncthreads();
    fft_row(x1r, x1i, S, tt, ws + (long)(row0 + 1) * LST);
}

// Kernel 2a: in-place prefix sum along channels. Thread owns (b, lag); 160 blocks
// (32 batches × 5 lag-chunks).
__global__ __launch_bounds__(128) void k2a_prefix(float* __restrict__ ws) {
    const int b = blockIdx.x / 5;
    const int l = (blockIdx.x % 5) * 128 + threadIdx.x;
    if (l >= NXC) return;
    float* base = ws + (long)b * 128 * LST + l;
    float run = 0.0f;
#pragma unroll 4
    for (int c = 0; c < 128; ++c) {
        run += base[c * LST];
        base[c * LST] = run;
    }
}

// Kernel 2b: windowed value from prefix difference, argmax/argmin with
// first-index tie-break, final cc/tshift + event passthrough.
__global__ __launch_bounds__(128) void k2b_pick(const float* __restrict__ ws,
                                                const int* __restrict__ e1,
                                                const int* __restrict__ e2,
                                                float* __restrict__ out) {
    const int bc = blockIdx.x;
    const int b = bc >> 7, c = bc & 127;
    const int t = threadIdx.x;
    const float* Pb = ws + (long)(b * 128) * LST;
    const float* hi = Pb + (long)min(c + 9, 127) * LST;
    const bool has_lo = (c >= 11);
    const float* lo = Pb + (long)(has_lo ? (c - 11) : 0) * LST;

    float vmax = -3.0e38f; int imax = 0;
    float vmin = 3.0e38f;  int imin = 0;
    for (int l = t; l < NXC; l += 128) {
        float s = hi[l] - (has_lo ? lo[l] : 0.0f);
        s *= (1.0f / 20.0f);
        if (s > vmax) { vmax = s; imax = l; }
        if (s < vmin) { vmin = s; imin = l; }
    }

    __shared__ float smax[128], smin[128];
    __shared__ int   sxi[128], sni[128];
    smax[t] = vmax; sxi[t] = imax; smin[t] = vmin; sni[t] = imin;
    __syncthreads();
    for (int off = 64; off > 0; off >>= 1) {
        if (t < off) {
            float v2 = smax[t + off]; int i2 = sxi[t + off];
            if (v2 > smax[t] || (v2 == smax[t] && i2 < sxi[t])) { smax[t] = v2; sxi[t] = i2; }
            float u2 = smin[t + off]; int j2 = sni[t + off];
            if (u2 < smin[t] || (u2 == smin[t] && j2 < sni[t])) { smin[t] = u2; sni[t] = j2; }
        }
        __syncthreads();
    }
    if (t == 0) {
        float vx = smax[0], vn = smin[0];
        int ix = sxi[0], in_ = sni[0];
        bool ineg = fabsf(vn) > vx;
        float ccv = ineg ? vn : vx;
        int idx = ineg ? in_ : ix;
        out[bc] = ccv;
        out[4096 + bc] = (float)(idx - 299) * 0.01f;   // (idx - NLAG + 1) * DT
    }
    if (bc == 0 && t < 32) out[8192 + t] = (float)e1[t];
    if (bc == 1 && t < 32) out[8224 + t] = (float)e2[t];
}

extern "C" void kernel_launch(void* const* d_in, const int* in_sizes, int n_in,
                              void* d_out, int out_size, void* d_ws, size_t ws_size,
                              hipStream_t stream) {
    const float2* d1 = (const float2*)d_in[0];
    const float2* d2 = (const float2*)d_in[1];
    const int* e1 = (const int*)d_in[2];
    const int* e2 = (const int*)d_in[3];
    float* out = (float*)d_out;
    float* ws = (float*)d_ws;

    k1_fft<<<dim3(2048), dim3(128), 0, stream>>>(d1, d2, ws);
    k2a_prefix<<<dim3(160), dim3(128), 0, stream>>>(ws);
    k2b_pick<<<dim3(4096), dim3(128), 0, stream>>>(ws, e1, e2, out);
}

// Round 7
// 49.957 us; speedup vs baseline: 3.3548x; 3.3548x over previous
//
#include <hip/hip_runtime.h>
#include <math.h>

// Problem constants
#define NBINS 2049       // F
#define NXC   599        // 2*NLAG-1
#define LST   640        // ws row stride (floats)
#define TWO_PI 6.283185307179586f

// complex LDS padding: +2 complex per 64. All accesses below use hand-folded
// base + literal-offset forms (verified against CPAD at sample points) so the
// compiler emits ds ops with immediate offsets, no per-access pad arithmetic.
#define CPAD(c) ((c) + 2 * ((c) >> 6))
#define OFF2(jj) (8 * (jj) + 2 * ((jj) >> 3))   // stage-2 offset, literal per jj

struct cpx { float r, i; };
__device__ inline cpx cmul(cpx a, cpx b) { return cpx{a.r * b.r - a.i * b.i, a.r * b.i + a.i * b.r}; }

__device__ inline void dft4i(float& r0, float& i0, float& r1, float& i1,
                             float& r2, float& i2, float& r3, float& i3) {
    float t0r = r0 + r2, t0i = i0 + i2;
    float t1r = r0 - r2, t1i = i0 - i2;
    float t2r = r1 + r3, t2i = i1 + i3;
    float t3r = r1 - r3, t3i = i1 - i3;
    r0 = t0r + t2r; i0 = t0i + t2i;
    r2 = t0r - t2r; i2 = t0i - t2i;
    r1 = t1r - t3i; i1 = t1i + t3r;
    r3 = t1r + t3i; i3 = t1i - t3r;
}

__device__ inline void radix8_bfly(float r[8], float im[8]) {
    float er0 = r[0], ei0 = im[0], er1 = r[2], ei1 = im[2];
    float er2 = r[4], ei2 = im[4], er3 = r[6], ei3 = im[6];
    float or0 = r[1], oi0 = im[1], or1 = r[3], oi1 = im[3];
    float or2 = r[5], oi2 = im[5], or3 = r[7], oi3 = im[7];
    dft4i(er0, ei0, er1, ei1, er2, ei2, er3, ei3);
    dft4i(or0, oi0, or1, oi1, or2, oi2, or3, oi3);
    const float C = 0.70710678118654752f;
    float w1r = C * (or1 - oi1), w1i = C * (or1 + oi1);
    float w2r = -oi2,            w2i = or2;
    float w3r = -C * (or3 + oi3), w3i = C * (or3 - oi3);
    r[0] = er0 + or0; im[0] = ei0 + oi0;
    r[4] = er0 - or0; im[4] = ei0 - oi0;
    r[1] = er1 + w1r; im[1] = ei1 + w1i;
    r[5] = er1 - w1r; im[5] = ei1 - w1i;
    r[2] = er2 + w2r; im[2] = ei2 + w2i;
    r[6] = er2 - w2r; im[6] = ei2 - w2i;
    r[3] = er3 + w3r; im[3] = ei3 + w3i;
    r[7] = er3 - w3r; im[7] = ei3 - w3i;
}

// inverse 16-point DFT, natural order in/out
__device__ inline void dft16i(float xr[16], float xi[16]) {
    float er[8], ei[8], odr[8], odi[8];
#pragma unroll
    for (int k = 0; k < 8; ++k) {
        er[k] = xr[2 * k];      ei[k] = xi[2 * k];
        odr[k] = xr[2 * k + 1]; odi[k] = xi[2 * k + 1];
    }
    radix8_bfly(er, ei);
    radix8_bfly(odr, odi);
    const float c1 = 0.92387953251128675613f;
    const float s1 = 0.38268343236508977173f;
    const float C  = 0.70710678118654752440f;
    float tr[8], td[8];
    tr[0] = odr[0];                      td[0] = odi[0];
    tr[1] = c1 * odr[1] - s1 * odi[1];   td[1] = c1 * odi[1] + s1 * odr[1];
    tr[2] = C * (odr[2] - odi[2]);       td[2] = C * (odr[2] + odi[2]);
    tr[3] = s1 * odr[3] - c1 * odi[3];   td[3] = s1 * odi[3] + c1 * odr[3];
    tr[4] = -odi[4];                     td[4] = odr[4];
    tr[5] = -s1 * odr[5] - c1 * odi[5];  td[5] = -s1 * odi[5] + c1 * odr[5];
    tr[6] = -C * (odr[6] + odi[6]);      td[6] = C * (odr[6] - odi[6]);
    tr[7] = -c1 * odr[7] - s1 * odi[7];  td[7] = -c1 * odi[7] + s1 * odr[7];
#pragma unroll
    for (int k = 0; k < 8; ++k) {
        xr[k]     = er[k] + tr[k];  xi[k]     = ei[k] + td[k];
        xr[k + 8] = er[k] - tr[k];  xi[k + 8] = ei[k] - td[k];
    }
}

// Apply w^k (k=1..15), w = (cs, sn). Log-depth product tree.
__device__ inline void apply_tw15(float zr[16], float zi[16], float cs, float sn) {
    cpx w[16];
    w[1]  = cpx{cs, sn};
    w[2]  = cmul(w[1], w[1]);
    w[3]  = cmul(w[1], w[2]);
    w[4]  = cmul(w[2], w[2]);
    w[5]  = cmul(w[2], w[3]);
    w[6]  = cmul(w[3], w[3]);
    w[7]  = cmul(w[3], w[4]);
    w[8]  = cmul(w[4], w[4]);
    w[9]  = cmul(w[4], w[5]);
    w[10] = cmul(w[5], w[5]);
    w[11] = cmul(w[5], w[6]);
    w[12] = cmul(w[6], w[6]);
    w[13] = cmul(w[6], w[7]);
    w[14] = cmul(w[7], w[7]);
    w[15] = cmul(w[7], w[8]);
#pragma unroll
    for (int k = 1; k < 16; ++k) {
        float a = zr[k] * w[k].r - zi[k] * w[k].i;
        float b = zr[k] * w[k].i + zi[k] * w[k].r;
        zr[k] = a; zi[k] = b;
    }
}

// Kernel 1: one (b,c) row per 128-thread block.
// Phase 0: ALL 32 global loads issued before any consumer (MLP), then
// X = h*conj(c1)*c2 into regs + LDS. Pack mirrors from LDS. 2048-pt inverse
// FFT radix 16/16/8, 2 LDS exchanges, folded lag store.
__global__ __launch_bounds__(128, 4) void k1_fft(const float2* __restrict__ d1,
                                                 const float2* __restrict__ d2,
                                                 float* __restrict__ ws) {
    __shared__ float2 S[2113];   // CPAD(0..2047) + slot 2112 (bin 2048); 16.9 KB
    const int row = blockIdx.x;  // b*128 + c
    const int tt = threadIdx.x;  // 0..127
    const float2* p1 = d1 + (long)row * NBINS;
    const float2* p2 = d2 + (long)row * NBINS;
    const float h = 2.44140625e-4f;   // 0.5/2048 (irfft scale folded into X)

    // folded LDS bases (verified vs CPAD): own/stage1 PT, mirror PU, stage2 B2, stage3 B3
    const int PT = tt + 2 * (tt >> 6);                   // CPAD(tt+128k) = PT + 132k
    const int PU = (2048 - tt) + 2 * ((2048 - tt) >> 6); // CPAD(2048-tt-128j) = PU - 132j
    const int s2 = tt >> 3, i2 = tt & 7;
    const int B2 = 132 * s2 + i2;                        // CPAD(128*s2+i2+8jj) = B2 + OFF2(jj)
    const int B3 = 16 * tt + 2 * (tt >> 2);              // CPAD(16tt+2r) = B3 + 2r

    // ---- phase 0a: issue ALL loads (independent; ~64 VGPRs transient) ----
    float2 a[16], b[16];
#pragma unroll
    for (int j = 0; j < 16; ++j) a[j] = p1[tt + 128 * j];
#pragma unroll
    for (int j = 0; j < 16; ++j) b[j] = p2[tt + 128 * j];
    float2 nyA, nyB;
    if (tt == 127) { nyA = p1[2048]; nyB = p2[2048]; }

    // ---- phase 0b: cross-spectrum → regs + LDS ----
    float xr_[16], xi_[16];
#pragma unroll
    for (int j = 0; j < 16; ++j) {
        float xr = h * (a[j].x * b[j].x + a[j].y * b[j].y);
        float xi = h * (a[j].x * b[j].y - a[j].y * b[j].x);
        if (tt == 0 && j == 0) xi = 0.0f;   // bin 0 imag zeroed
        xr_[j] = xr; xi_[j] = xi;
        S[PT + 132 * j] = make_float2(xr, xi);
    }
    if (tt == 127)   // bin 2048 (Nyquist), imag zeroed
        S[2112] = make_float2(h * (nyA.x * nyB.x + nyA.y * nyB.y), 0.0f);
    __syncthreads();

    // ---- pack: Z[c] = E + i*t_c*D, mirror X[2048-c] from LDS ----
    const float WC[16] = { 1.0f, 0.98078528040323044913f, 0.92387953251128675613f,
        0.83146961230254523708f, 0.70710678118654752440f, 0.55557023301960222474f,
        0.38268343236508977173f, 0.19509032201612826785f, 0.0f,
        -0.19509032201612826785f, -0.38268343236508977173f, -0.55557023301960222474f,
        -0.70710678118654752440f, -0.83146961230254523708f, -0.92387953251128675613f,
        -0.98078528040323044913f };
    const float WS[16] = { 0.0f, 0.19509032201612826785f, 0.38268343236508977173f,
        0.55557023301960222474f, 0.70710678118654752440f, 0.83146961230254523708f,
        0.92387953251128675613f, 0.98078528040323044913f, 1.0f,
        0.98078528040323044913f, 0.92387953251128675613f, 0.83146961230254523708f,
        0.70710678118654752440f, 0.55557023301960222474f, 0.38268343236508977173f,
        0.19509032201612826785f };
    float zr[16], zi[16];
    float sn, cs;
    __sincosf((float)tt * (TWO_PI / 4096.0f), &sn, &cs);
#pragma unroll
    for (int j = 0; j < 16; ++j) {
        float2 m = S[PU - 132 * j];
        float er = xr_[j] + m.x, ei = xi_[j] - m.y;
        float dr = xr_[j] - m.x, di = xi_[j] + m.y;
        float twr = cs * WC[j] - sn * WS[j];
        float twi = cs * WS[j] + sn * WC[j];
        zr[j] = er - twi * dr - twr * di;
        zi[j] = ei + twr * dr - twi * di;
    }

    // ---- stage 1: L=2048, radix-16, span=128 ----
    dft16i(zr, zi);
    __sincosf((float)tt * (TWO_PI / 2048.0f), &sn, &cs);
    apply_tw15(zr, zi, cs, sn);
    __syncthreads();   // all mirror reads complete before overwrite
#pragma unroll
    for (int k = 0; k < 16; ++k)
        S[PT + 132 * k] = make_float2(zr[k], zi[k]);
    __syncthreads();

    // ---- stage 2: L=128, radix-16, span=8; per-thread in-place ----
#pragma unroll
    for (int jj = 0; jj < 16; ++jj) {
        float2 v = S[B2 + OFF2(jj)];
        zr[jj] = v.x; zi[jj] = v.y;
    }
    dft16i(zr, zi);
    __sincosf((float)i2 * (TWO_PI / 128.0f), &sn, &cs);
    apply_tw15(zr, zi, cs, sn);
#pragma unroll
    for (int k = 0; k < 16; ++k)
        S[B2 + OFF2(k)] = make_float2(zr[k], zi[k]);
    __syncthreads();

    // ---- stage 3: L=8, radix-8 on sub-blocks sb = 2tt, 2tt+1 ----
    float ar[8], ai[8], br[8], bi[8];
    const float4* S3 = (const float4*)(S + B3);
#pragma unroll
    for (int r = 0; r < 4; ++r) {
        float4 v = S3[r];
        ar[2 * r] = v.x; ai[2 * r] = v.y; ar[2 * r + 1] = v.z; ai[2 * r + 1] = v.w;
    }
#pragma unroll
    for (int r = 0; r < 4; ++r) {
        float4 v = S3[r + 4];
        br[2 * r] = v.x; bi[2 * r] = v.y; br[2 * r + 1] = v.z; bi[2 * r + 1] = v.w;
    }
    radix8_bfly(ar, ai);   // only y[0], y[7] consumed; DCE trims the rest
    radix8_bfly(br, bi);

    // sub-block sb = 16*k1 + k2 holds spectral m = m0 + 256*k3, m0 = k1 + 16*k2.
    // lag map: m0<=149: Re->l=2m0+299, Im->l=2m0+300 (y[0]);
    //          m0>=107: Re->l=2m0-213, Im->l=2m0-212 (y[7]); m0==106: Im->l=0.
    float* wrow = ws + (long)row * LST;
    {
        int sb = 2 * tt;
        int m0 = (sb >> 4) + 16 * (sb & 15);
        if (m0 <= 149) { wrow[2 * m0 + 299] = ar[0]; wrow[2 * m0 + 300] = ai[0]; }
        if (m0 >= 107)      { wrow[2 * m0 - 213] = ar[7]; wrow[2 * m0 - 212] = ai[7]; }
        else if (m0 == 106) { wrow[0] = ai[7]; }
    }
    {
        int sb = 2 * tt + 1;
        int m0 = (sb >> 4) + 16 * (sb & 15);
        if (m0 <= 149) { wrow[2 * m0 + 299] = br[0]; wrow[2 * m0 + 300] = bi[0]; }
        if (m0 >= 107)      { wrow[2 * m0 - 213] = br[7]; wrow[2 * m0 - 212] = bi[7]; }
        else if (m0 == 106) { wrow[0] = bi[7]; }
    }
}

// Kernel 2a: in-place prefix sum along channels. Thread owns (b, lag).
__global__ __launch_bounds__(128) void k2a_prefix(float* __restrict__ ws) {
    const int b = blockIdx.x / 5;
    const int l = (blockIdx.x % 5) * 128 + threadIdx.x;
    if (l >= NXC) return;
    float* base = ws + (long)b * 128 * LST + l;
    float run = 0.0f;
#pragma unroll 4
    for (int c = 0; c < 128; ++c) {
        run += base[c * LST];
        base[c * LST] = run;
    }
}

// Kernel 2b: windowed value from prefix difference, argmax/argmin with
// first-index tie-break, final cc/tshift + event passthrough.
__global__ __launch_bounds__(128) void k2b_pick(const float* __restrict__ ws,
                                                const int* __restrict__ e1,
                                                const int* __restrict__ e2,
                                                float* __restrict__ out) {
    const int bc = blockIdx.x;
    const int b = bc >> 7, c = bc & 127;
    const int t = threadIdx.x;
    const float* Pb = ws + (long)(b * 128) * LST;
    const float* hi = Pb + (long)min(c + 9, 127) * LST;
    const bool has_lo = (c >= 11);
    const float* lo = Pb + (long)(has_lo ? (c - 11) : 0) * LST;

    float vmax = -3.0e38f; int imax = 0;
    float vmin = 3.0e38f;  int imin = 0;
    for (int l = t; l < NXC; l += 128) {
        float s = hi[l] - (has_lo ? lo[l] : 0.0f);
        s *= (1.0f / 20.0f);
        if (s > vmax) { vmax = s; imax = l; }
        if (s < vmin) { vmin = s; imin = l; }
    }

    __shared__ float smax[128], smin[128];
    __shared__ int   sxi[128], sni[128];
    smax[t] = vmax; sxi[t] = imax; smin[t] = vmin; sni[t] = imin;
    __syncthreads();
    for (int off = 64; off > 0; off >>= 1) {
        if (t < off) {
            float v2 = smax[t + off]; int i2 = sxi[t + off];
            if (v2 > smax[t] || (v2 == smax[t] && i2 < sxi[t])) { smax[t] = v2; sxi[t] = i2; }
            float u2 = smin[t + off]; int j2 = sni[t + off];
            if (u2 < smin[t] || (u2 == smin[t] && j2 < sni[t])) { smin[t] = u2; sni[t] = j2; }
        }
        __syncthreads();
    }
    if (t == 0) {
        float vx = smax[0], vn = smin[0];
        int ix = sxi[0], in_ = sni[0];
        bool ineg = fabsf(vn) > vx;
        float ccv = ineg ? vn : vx;
        int idx = ineg ? in_ : ix;
        out[bc] = ccv;
        out[4096 + bc] = (float)(idx - 299) * 0.01f;   // (idx - NLAG + 1) * DT
    }
    if (bc == 0 && t < 32) out[8192 + t] = (float)e1[t];
    if (bc == 1 && t < 32) out[8224 + t] = (float)e2[t];
}

extern "C" void kernel_launch(void* const* d_in, const int* in_sizes, int n_in,
                              void* d_out, int out_size, void* d_ws, size_t ws_size,
                              hipStream_t stream) {
    const float2* d1 = (const float2*)d_in[0];
    const float2* d2 = (const float2*)d_in[1];
    const int* e1 = (const int*)d_in[2];
    const int* e2 = (const int*)d_in[3];
    float* out = (float*)d_out;
    float* ws = (float*)d_ws;

    k1_fft<<<dim3(4096), dim3(128), 0, stream>>>(d1, d2, ws);
    k2a_prefix<<<dim3(160), dim3(128), 0, stream>>>(ws);
    k2b_pick<<<dim3(4096), dim3(128), 0, stream>>>(ws, e1, e2, out);
}

// Round 8
// 49.425 us; speedup vs baseline: 3.3909x; 1.0108x over previous
//
#include <hip/hip_runtime.h>
#include <math.h>

// Problem constants
#define NBINS 2049       // F
#define NXC   599        // 2*NLAG-1
#define LST   640        // ws row stride (floats)
#define TWO_PI 6.283185307179586f

// complex LDS padding: +2 complex per 64; all hot accesses use hand-folded
// base + literal-offset forms (each verified against CPAD at sample points).
#define CPAD(c) ((c) + 2 * ((c) >> 6))

struct cpx { float r, i; };
__device__ inline cpx cmul(cpx a, cpx b) { return cpx{a.r * b.r - a.i * b.i, a.r * b.i + a.i * b.r}; }

__device__ inline void dft4i(float& r0, float& i0, float& r1, float& i1,
                             float& r2, float& i2, float& r3, float& i3) {
    float t0r = r0 + r2, t0i = i0 + i2;
    float t1r = r0 - r2, t1i = i0 - i2;
    float t2r = r1 + r3, t2i = i1 + i3;
    float t3r = r1 - r3, t3i = i1 - i3;
    r0 = t0r + t2r; i0 = t0i + t2i;
    r2 = t0r - t2r; i2 = t0i - t2i;
    r1 = t1r - t3i; i1 = t1i + t3r;
    r3 = t1r + t3i; i3 = t1i - t3r;
}

__device__ inline void radix8_bfly(float r[8], float im[8]) {
    float er0 = r[0], ei0 = im[0], er1 = r[2], ei1 = im[2];
    float er2 = r[4], ei2 = im[4], er3 = r[6], ei3 = im[6];
    float or0 = r[1], oi0 = im[1], or1 = r[3], oi1 = im[3];
    float or2 = r[5], oi2 = im[5], or3 = r[7], oi3 = im[7];
    dft4i(er0, ei0, er1, ei1, er2, ei2, er3, ei3);
    dft4i(or0, oi0, or1, oi1, or2, oi2, or3, oi3);
    const float C = 0.70710678118654752f;
    float w1r = C * (or1 - oi1), w1i = C * (or1 + oi1);
    float w2r = -oi2,            w2i = or2;
    float w3r = -C * (or3 + oi3), w3i = C * (or3 - oi3);
    r[0] = er0 + or0; im[0] = ei0 + oi0;
    r[4] = er0 - or0; im[4] = ei0 - oi0;
    r[1] = er1 + w1r; im[1] = ei1 + w1i;
    r[5] = er1 - w1r; im[5] = ei1 - w1i;
    r[2] = er2 + w2r; im[2] = ei2 + w2i;
    r[6] = er2 - w2r; im[6] = ei2 - w2i;
    r[3] = er3 + w3r; im[3] = ei3 + w3i;
    r[7] = er3 - w3r; im[7] = ei3 - w3i;
}

// Apply w^k (k=1..7), w = (cs, sn). Log-depth tree; 7 independent final multiplies.
__device__ inline void apply_tw7(float zr[8], float zi[8], float cs, float sn) {
    cpx w[8];
    w[1] = cpx{cs, sn};
    w[2] = cmul(w[1], w[1]);
    w[3] = cmul(w[1], w[2]);
    w[4] = cmul(w[2], w[2]);
    w[5] = cmul(w[2], w[3]);
    w[6] = cmul(w[3], w[3]);
    w[7] = cmul(w[3], w[4]);
#pragma unroll
    for (int k = 1; k < 8; ++k) {
        float a = zr[k] * w[k].r - zi[k] * w[k].i;
        float b = zr[k] * w[k].i + zi[k] * w[k].r;
        zr[k] = a; zi[k] = b;
    }
}

// Kernel 1: one (b,c) row per 256-thread block (4 waves). In-place DIF chain
// radix 8/8/8/4 (spans 256/32/4/1; round-1-verified layout: output m at
// storage 256(m&7)+32((m>>3)&7)+4((m>>6)&7)+(m>>9)). Burst loads (16 dwordx2
// = 32 VGPR, sched_barrier pinned), LDS-mirror pack, partial final stage.
__global__ __launch_bounds__(256, 5) void k1_fft(const float2* __restrict__ d1,
                                                 const float2* __restrict__ d2,
                                                 float* __restrict__ ws) {
    __shared__ float2 S[2113];   // CPAD(0..2047) + slot 2112 (bin 2048); 16.9 KB
    const int row = blockIdx.x;  // b*128 + c
    const int tt = threadIdx.x;  // 0..255
    const float2* p1 = d1 + (long)row * NBINS;
    const float2* p2 = d2 + (long)row * NBINS;
    const float h = 2.44140625e-4f;   // 0.5/2048 (irfft scale folded into X)

    // folded LDS bases (each verified vs CPAD):
    const int PT = tt + 2 * (tt >> 6);                    // CPAD(tt+256j)      = PT + 264j
    const int PU = (2048 - tt) + 2 * ((2048 - tt) >> 6);  // CPAD(2048-tt-256j) = PU - 264j
    const int i2 = tt & 31;
    const int B2 = 264 * (tt >> 5) + i2;                  // CPAD(256(tt>>5)+i2+32j) = B2 + 32j + 2(j>>1)
    const int i3 = tt & 3;
    const int B3 = 32 * (tt >> 2) + 2 * (tt >> 3) + i3;   // CPAD(32(tt>>2)+i3+4j)   = B3 + 4j

    // ---- phase 0a: burst ALL 16 loads; pin them before any consumer ----
    float2 a[8], b[8];
#pragma unroll
    for (int j = 0; j < 8; ++j) a[j] = p1[tt + 256 * j];
#pragma unroll
    for (int j = 0; j < 8; ++j) b[j] = p2[tt + 256 * j];
    float2 nyA, nyB;
    if (tt == 255) { nyA = p1[2048]; nyB = p2[2048]; }
    __builtin_amdgcn_sched_barrier(0);

    // ---- phase 0b: X = h*conj(c1)*c2 → regs + LDS (mirror source) ----
    float xr_[8], xi_[8];
#pragma unroll
    for (int j = 0; j < 8; ++j) {
        float xr = h * (a[j].x * b[j].x + a[j].y * b[j].y);
        float xi = h * (a[j].x * b[j].y - a[j].y * b[j].x);
        if (tt == 0 && j == 0) xi = 0.0f;   // bin 0 imag zeroed
        xr_[j] = xr; xi_[j] = xi;
        S[PT + 264 * j] = make_float2(xr, xi);
    }
    if (tt == 255)   // bin 2048 (Nyquist), imag zeroed (pocketfft c2r)
        S[2112] = make_float2(h * (nyA.x * nyB.x + nyA.y * nyB.y), 0.0f);
    __syncthreads();

    // ---- pack: Z[c] = E + i*t_c*D; mirror X[2048-c] from LDS ----
    // t_c = e^{2pi i tt/4096} * e^{2pi i j/16} (j-factor from literal table)
    const float WC8[8] = { 1.0f, 0.92387953251128675613f, 0.70710678118654752440f,
        0.38268343236508977173f, 0.0f, -0.38268343236508977173f,
        -0.70710678118654752440f, -0.92387953251128675613f };
    const float WS8[8] = { 0.0f, 0.38268343236508977173f, 0.70710678118654752440f,
        0.92387953251128675613f, 1.0f, 0.92387953251128675613f,
        0.70710678118654752440f, 0.38268343236508977173f };
    float zr[8], zi[8], sn, cs;
    __sincosf((float)tt * (TWO_PI / 4096.0f), &sn, &cs);
#pragma unroll
    for (int j = 0; j < 8; ++j) {
        float2 m = S[PU - 264 * j];   // tt=0,j=0 → slot 2112 (bin 2048)
        float er = xr_[j] + m.x, ei = xi_[j] - m.y;
        float dr = xr_[j] - m.x, di = xi_[j] + m.y;
        float twr = cs * WC8[j] - sn * WS8[j];
        float twi = cs * WS8[j] + sn * WC8[j];
        zr[j] = er - twi * dr - twr * di;
        zi[j] = ei + twr * dr - twi * di;
    }

    // ---- stage 1: L=2048, span=256, i=tt (inputs already in regs) ----
    radix8_bfly(zr, zi);
    __sincosf((float)tt * (TWO_PI / 2048.0f), &sn, &cs);
    apply_tw7(zr, zi, cs, sn);
    __syncthreads();   // all mirror reads complete before overwrite
#pragma unroll
    for (int k = 0; k < 8; ++k)
        S[PT + 264 * k] = make_float2(zr[k], zi[k]);
    __syncthreads();

    // ---- stage 2: L=256, span=32, i = tt&31; per-thread in-place ----
#pragma unroll
    for (int j = 0; j < 8; ++j) {
        float2 v = S[B2 + 32 * j + 2 * (j >> 1)];
        zr[j] = v.x; zi[j] = v.y;
    }
    radix8_bfly(zr, zi);
    __sincosf((float)i2 * (TWO_PI / 256.0f), &sn, &cs);
    apply_tw7(zr, zi, cs, sn);
#pragma unroll
    for (int k = 0; k < 8; ++k)
        S[B2 + 32 * k + 2 * (k >> 1)] = make_float2(zr[k], zi[k]);
    __syncthreads();

    // ---- stage 3: L=32, span=4, i = tt&3; per-thread in-place ----
#pragma unroll
    for (int j = 0; j < 8; ++j) {
        float2 v = S[B3 + 4 * j];
        zr[j] = v.x; zi[j] = v.y;
    }
    radix8_bfly(zr, zi);
    __sincosf((float)i3 * (TWO_PI / 32.0f), &sn, &cs);
    apply_tw7(zr, zi, cs, sn);
#pragma unroll
    for (int k = 0; k < 8; ++k)
        S[B3 + 4 * k] = make_float2(zr[k], zi[k]);
    __syncthreads();

    // ---- stage 4: radix-4, span=1, butterflies u = tt, tt+256 ----
    // storage: output m = m0 + 512*k4 at pos 4u + k4, m0 = (u>>6)+8*((u>>3)&7)+64*(u&7).
    // Needed: k4=0 (y0): m0<=149 → Re l=2m0+299, Im l=2m0+300;
    //         k4=3 (y3): m0>=363 → Re l=2m0-725, Im l=2m0-724; m0==362 → Im l=0.
    float* wrow = ws + (long)row * LST;
#pragma unroll
    for (int hh = 0; hh < 2; ++hh) {
        const int u = tt + 256 * hh;
        const int cb = 4 * u + 2 * (u >> 4);   // CPAD(4u); 4u..4u+3 contiguous
        float4 v0 = *(const float4*)&S[cb];        // x0, x1
        float4 v1 = *(const float4*)&S[cb + 2];    // x2, x3
        float y0r = (v0.x + v1.x) + (v0.z + v1.z);
        float y0i = (v0.y + v1.y) + (v0.w + v1.w);
        float t1r = v0.x - v1.x, t1i = v0.y - v1.y;
        float t3r = v0.z - v1.z, t3i = v0.w - v1.w;
        float y3r = t1r + t3i, y3i = t1i - t3r;
        const int m0 = (u >> 6) + 8 * ((u >> 3) & 7) + 64 * (u & 7);
        if (m0 <= 149) { wrow[2 * m0 + 299] = y0r; wrow[2 * m0 + 300] = y0i; }
        if (m0 >= 363)      { wrow[2 * m0 - 725] = y3r; wrow[2 * m0 - 724] = y3i; }
        else if (m0 == 362) { wrow[0] = y3i; }
    }
}

// Kernel 2a: in-place prefix sum along channels. Thread owns (b, lag).
__global__ __launch_bounds__(128) void k2a_prefix(float* __restrict__ ws) {
    const int b = blockIdx.x / 5;
    const int l = (blockIdx.x % 5) * 128 + threadIdx.x;
    if (l >= NXC) return;
    float* base = ws + (long)b * 128 * LST + l;
    float run = 0.0f;
#pragma unroll 4
    for (int c = 0; c < 128; ++c) {
        run += base[c * LST];
        base[c * LST] = run;
    }
}

// Kernel 2b: windowed value from prefix difference, argmax/argmin with
// first-index tie-break, final cc/tshift + event passthrough.
__global__ __launch_bounds__(128) void k2b_pick(const float* __restrict__ ws,
                                                const int* __restrict__ e1,
                                                const int* __restrict__ e2,
                                                float* __restrict__ out) {
    const int bc = blockIdx.x;
    const int b = bc >> 7, c = bc & 127;
    const int t = threadIdx.x;
    const float* Pb = ws + (long)(b * 128) * LST;
    const float* hi = Pb + (long)min(c + 9, 127) * LST;
    const bool has_lo = (c >= 11);
    const float* lo = Pb + (long)(has_lo ? (c - 11) : 0) * LST;

    float vmax = -3.0e38f; int imax = 0;
    float vmin = 3.0e38f;  int imin = 0;
    for (int l = t; l < NXC; l += 128) {
        float s = hi[l] - (has_lo ? lo[l] : 0.0f);
        s *= (1.0f / 20.0f);
        if (s > vmax) { vmax = s; imax = l; }
        if (s < vmin) { vmin = s; imin = l; }
    }

    __shared__ float smax[128], smin[128];
    __shared__ int   sxi[128], sni[128];
    smax[t] = vmax; sxi[t] = imax; smin[t] = vmin; sni[t] = imin;
    __syncthreads();
    for (int off = 64; off > 0; off >>= 1) {
        if (t < off) {
            float v2 = smax[t + off]; int ii = sxi[t + off];
            if (v2 > smax[t] || (v2 == smax[t] && ii < sxi[t])) { smax[t] = v2; sxi[t] = ii; }
            float u2 = smin[t + off]; int jj = sni[t + off];
            if (u2 < smin[t] || (u2 == smin[t] && jj < sni[t])) { smin[t] = u2; sni[t] = jj; }
        }
        __syncthreads();
    }
    if (t == 0) {
        float vx = smax[0], vn = smin[0];
        int ix = sxi[0], in_ = sni[0];
        bool ineg = fabsf(vn) > vx;
        float ccv = ineg ? vn : vx;
        int idx = ineg ? in_ : ix;
        out[bc] = ccv;
        out[4096 + bc] = (float)(idx - 299) * 0.01f;   // (idx - NLAG + 1) * DT
    }
    if (bc == 0 && t < 32) out[8192 + t] = (float)e1[t];
    if (bc == 1 && t < 32) out[8224 + t] = (float)e2[t];
}

extern "C" void kernel_launch(void* const* d_in, const int* in_sizes, int n_in,
                              void* d_out, int out_size, void* d_ws, size_t ws_size,
                              hipStream_t stream) {
    const float2* d1 = (const float2*)d_in[0];
    const float2* d2 = (const float2*)d_in[1];
    const int* e1 = (const int*)d_in[2];
    const int* e2 = (const int*)d_in[3];
    float* out = (float*)d_out;
    float* ws = (float*)d_ws;

    k1_fft<<<dim3(4096), dim3(256), 0, stream>>>(d1, d2, ws);
    k2a_prefix<<<dim3(160), dim3(128), 0, stream>>>(ws);
    k2b_pick<<<dim3(4096), dim3(128), 0, stream>>>(ws, e1, e2, out);
}